// Round 5
// baseline (697.424 us; speedup 1.0000x reference)
//
#include <hip/hip_runtime.h>
#include <cmath>
#include <cstddef>

#define BATCH 8
#define CH    3
#define HH    512
#define WW    512
#define NSLOT 7
#define HWX   (HH*WW)

__device__ __host__ __forceinline__ int refl(int i, int n) {
    i = i < 0 ? -i : i;
    return i >= n ? 2 * n - 2 - i : i;
}

// ---------------- compile-time Gaussian weights -----------------
constexpr double cexp_(double x) {           // e^x for x in [-13, 0]
    double r = x / 64.0, term = 1.0, s = 1.0;
    for (int i = 1; i < 26; ++i) { term *= r / i; s += term; }
    for (int j = 0; j < 6; ++j) s *= s;      // s = (e^{x/64})^64
    return s;
}

// h-pass weights: effective size KSE = KS + Z (Z zero taps prepended so the
// staged row's left pad is a multiple of 4 floats). Real taps at [8+Z, 8+KSE).
template<int KSE> struct WArr { float w[KSE + 16]; };

template<int KSE, int KS>
constexpr WArr<KSE> make_wz(double sg) {
    WArr<KSE> a{};
    double tmp[KS] = {};
    double sum = 0.0;
    for (int t = 0; t < KS; ++t) {
        const double ax = (double)(t - KS / 2);
        tmp[t] = cexp_(-(ax * ax) / (2.0 * sg * sg));
        sum += tmp[t];
    }
    for (int i = 0; i < KSE + 16; ++i) a.w[i] = 0.0f;
    constexpr int Z = KSE - KS;
    for (int t = 0; t < KS; ++t) a.w[8 + Z + t] = (float)(tmp[t] / sum);
    return a;
}

// per scale: KS {7,9,17,31,59,117}, PD=KS/2 {3,4,8,15,29,58}
// PDA = round-up-4 {4,4,8,16,32,60}; Z = PDA-PD {1,0,0,1,3,2}; KSE = KS+Z
__device__ constexpr WArr<8>   CW0 = make_wz<8,   7>(0.6);
__device__ constexpr WArr<9>   CW1 = make_wz<9,   9>(1.2);
__device__ constexpr WArr<17>  CW2 = make_wz<17, 17>(2.4);
__device__ constexpr WArr<32>  CW3 = make_wz<32, 31>(4.8);
__device__ constexpr WArr<62>  CW4 = make_wz<62, 59>(9.6);
__device__ constexpr WArr<119> CW5 = make_wz<119,117>(19.2);

// v-pass weights: exact taps at [0, KS), compile-time indexed -> literals
template<int KS> struct CVArr { float w[KS]; };

template<int KS>
constexpr CVArr<KS> make_cv(double sg) {
    CVArr<KS> a{};
    double tmp[KS] = {};
    double sum = 0.0;
    for (int t = 0; t < KS; ++t) {
        const double ax = (double)(t - KS / 2);
        tmp[t] = cexp_(-(ax * ax) / (2.0 * sg * sg));
        sum += tmp[t];
    }
    for (int t = 0; t < KS; ++t) a.w[t] = (float)(tmp[t] / sum);
    return a;
}

__device__ constexpr CVArr<7>   CV0 = make_cv<7>(0.6);
__device__ constexpr CVArr<9>   CV1 = make_cv<9>(1.2);
__device__ constexpr CVArr<17>  CV2 = make_cv<17>(2.4);
__device__ constexpr CVArr<31>  CV3 = make_cv<31>(4.8);
__device__ constexpr CVArr<59>  CV4 = make_cv<59>(9.6);
__device__ constexpr CVArr<117> CV5 = make_cv<117>(19.2);

// ---------------- horizontal blur: 4 px/thread, 6-slot rolling window ----------------------
template<int KSE>
__device__ __forceinline__ float4 hblur4(const float* __restrict__ lrow, int xt,
                                         const WArr<KSE>& W)
{
    constexpr int NT = (KSE + 3) & ~3;
    constexpr int G  = NT / 4;           // tap groups
    constexpr int NR = G + 2;            // float4 slots needed: 0..G+1
    const float4* l4 = (const float4*)lrow;
    float cb[24];                        // 6 rolling float4 slots
#pragma unroll
    for (int s = 0; s < (NR < 4 ? NR : 4); ++s) {   // up-front prefetch
        const float4 t = l4[xt + s];
        cb[(s % 6) * 4 + 0] = t.x; cb[(s % 6) * 4 + 1] = t.y;
        cb[(s % 6) * 4 + 2] = t.z; cb[(s % 6) * 4 + 3] = t.w;
    }
    float a[4] = {0.f, 0.f, 0.f, 0.f};
#pragma unroll
    for (int g = 0; g < G; ++g) {
        if (g + 4 < NR) {                // read ahead (folds at unroll)
            const int sl = (g + 4) % 6;
            const float4 t = l4[xt + g + 4];
            cb[sl * 4 + 0] = t.x; cb[sl * 4 + 1] = t.y;
            cb[sl * 4 + 2] = t.z; cb[sl * 4 + 3] = t.w;
        }
#pragma unroll
        for (int tt = 0; tt < 4; ++tt) {
            const float wt = W.w[8 + 4 * g + tt];        // compile-time constant
#pragma unroll
            for (int j = 0; j < 4; ++j) {
                const int q    = tt + j;                 // 0..6
                const int slot = (g + (q >> 2)) % 6;
                a[j] = fmaf(wt, cb[slot * 4 + (q & 3)], a[j]);
            }
        }
    }
    return make_float4(a[0], a[1], a[2], a[3]);
}

// ---------------- fully fused kernel ---------------------------------------------------------
// One block = 128 threads = one row-pair (y, y+1). Phase V: each thread v-blurs its own
// 4 columns for all 6 scales directly from global img (L2-resident per-XCD), amortizing
// each img-row load across both rows and all scales. Store to LDS; halos filled by LDS
// reflection (v-blur commutes with x-reflection -> zero overcompute). Phase H: R3-proven
// h-blur + DoG chain, written once, final. NO intermediate global traffic at all.
// LDS layout per row (floats), left pad PDA (mult of 4):
// s:      0     1     2     3     4     5
// PDA:    4     4     8    16    32    60
// OFF:    0   524  1052  1588  2136  2716
// LEN:  524   528   536   548   580   636   (= NT + 516)
#define LDSROW 3352   // 2 rows = 26816 B/block -> 6 blocks/CU (12 waves)

__device__ __forceinline__ float4 f4sub(float4 a, float4 b) {
    return make_float4(a.x - b.x, a.y - b.y, a.z - b.z, a.w - b.w);
}

// i = t - (58 - PD) - j is the v-tap index; folds at unroll (t, j compile-time)
#define VTAP(s, KS, PD, W)                                                     \
    {                                                                          \
        const int i = t - (58 - PD) - j;                                       \
        if (i >= 0 && i < KS) {                                                \
            const float wt = W.w[i];         /* compile-time constant */       \
            acc[j][s][0] = fmaf(wt, v.x, acc[j][s][0]);                        \
            acc[j][s][1] = fmaf(wt, v.y, acc[j][s][1]);                        \
            acc[j][s][2] = fmaf(wt, v.z, acc[j][s][2]);                        \
            acc[j][s][3] = fmaf(wt, v.w, acc[j][s][3]);                        \
        }                                                                      \
    }

// halo fill by reflection of the already-staged interior (run by 64 lanes per row)
#define HALO(OFF, LEN, PDA)                                                    \
    {                                                                          \
        for (int i2 = u; i2 < PDA; i2 += 64)                                   \
            Lx[OFF + i2] = Lx[OFF + 2 * PDA - i2];                             \
        for (int i2 = PDA + 512 + u; i2 < LEN; i2 += 64)                       \
            Lx[OFF + i2] = Lx[OFF + 2 * PDA + 1022 - i2];                      \
    }

// 1-D grid, XCD-swizzled: 6144 = 8 xcd * 3 bcg * 256 row-pairs; per-XCD slice of
// img = 3 channel images (3 MB) -> L2-resident re-reads.
__global__ __launch_bounds__(128) void fused_dog_kernel(const float* __restrict__ img,
                                                        float* __restrict__ out)
{
    __shared__ __align__(16) float lds[2][LDSROW];
    const int xt  = threadIdx.x;         // 0..127 (float4 col)
    const int n   = blockIdx.x;
    const int xcd = n & 7;
    const int k   = n >> 3;              // 0..767
    const int bcg = k >> 8;              // 0..2
    const int y   = (k & 255) * 2;       // even row of the pair
    const int bc  = bcg * 8 + xcd;       // 0..23
    const int b = bc / CH, c = bc - b * CH;

    const float* ibase = img + (size_t)bc * HWX;

    // ---------------- phase V: 6-scale vertical blur for cols 4xt..4xt+3, rows y,y+1 ------
    float acc[2][6][4];
#pragma unroll
    for (int j = 0; j < 2; ++j)
#pragma unroll
        for (int s = 0; s < 6; ++s)
#pragma unroll
            for (int q = 0; q < 4; ++q) acc[j][s][q] = 0.f;

    float4 g0a = make_float4(0.f, 0.f, 0.f, 0.f);
    float4 g0b = make_float4(0.f, 0.f, 0.f, 0.f);

#pragma unroll
    for (int t = 0; t < 119; ++t) {
        const int yi = refl(y - 58 + t, HH);         // uniform -> SALU, saddr-form load
        const float4 v = ((const float4*)(ibase + (size_t)yi * WW))[xt];
        if (t == 58) g0a = v;                        // raw img row y   (g0 for DoG)
        if (t == 59) g0b = v;                        // raw img row y+1
#pragma unroll
        for (int j = 0; j < 2; ++j) {
            VTAP(0,   7,  3, CV0)
            VTAP(1,   9,  4, CV1)
            VTAP(2,  17,  8, CV2)
            VTAP(3,  31, 15, CV3)
            VTAP(4,  59, 29, CV4)
            VTAP(5, 117, 58, CV5)
        }
    }

    // bulk store of v-results (b128, conflict-free; OFF+PDA multiple of 4 floats)
#pragma unroll
    for (int j = 0; j < 2; ++j) {
        float* L = lds[j];
        ((float4*)(L +    0 +  4))[xt] = make_float4(acc[j][0][0], acc[j][0][1], acc[j][0][2], acc[j][0][3]);
        ((float4*)(L +  524 +  4))[xt] = make_float4(acc[j][1][0], acc[j][1][1], acc[j][1][2], acc[j][1][3]);
        ((float4*)(L + 1052 +  8))[xt] = make_float4(acc[j][2][0], acc[j][2][1], acc[j][2][2], acc[j][2][3]);
        ((float4*)(L + 1588 + 16))[xt] = make_float4(acc[j][3][0], acc[j][3][1], acc[j][3][2], acc[j][3][3]);
        ((float4*)(L + 2136 + 32))[xt] = make_float4(acc[j][4][0], acc[j][4][1], acc[j][4][2], acc[j][4][3]);
        ((float4*)(L + 2716 + 60))[xt] = make_float4(acc[j][5][0], acc[j][5][1], acc[j][5][2], acc[j][5][3]);
    }
    __syncthreads();

    // halo fill by reflection: lanes 0-63 -> row 0, lanes 64-127 -> row 1
    {
        const int u = xt & 63;
        float* Lx = lds[xt >> 6];
        HALO(   0, 524,  4)
        HALO( 524, 528,  4)
        HALO(1052, 536,  8)
        HALO(1588, 548, 16)
        HALO(2136, 580, 32)
        HALO(2716, 636, 60)
    }
    __syncthreads();

    // ---------------- phase H: h-blur + DoG chain, write final output ----------------------
    float4* out4 = (float4*)out;
#pragma unroll 1
    for (int j = 0; j < 2; ++j) {
        const float* L = lds[j];
        const size_t pbase = (size_t)(y + j) * (WW / 4) + xt;
#define OSL(s) (out4 + ((size_t)((b * NSLOT + (s)) * CH) + c) * (HWX / 4) + pbase)
        float4 gp = j ? g0b : g0a;
        float4 g;
        g = hblur4<  8>(L +    0, xt, CW0); *OSL(0) = f4sub(g, gp); gp = g;
        g = hblur4<  9>(L +  524, xt, CW1); *OSL(1) = f4sub(g, gp); gp = g;
        g = hblur4< 17>(L + 1052, xt, CW2); *OSL(2) = f4sub(g, gp); gp = g;
        g = hblur4< 32>(L + 1588, xt, CW3); *OSL(3) = f4sub(g, gp); gp = g;
        g = hblur4< 62>(L + 2136, xt, CW4); *OSL(4) = f4sub(g, gp); gp = g;
        g = hblur4<119>(L + 2716, xt, CW5); *OSL(5) = f4sub(g, gp);
        *OSL(6) = g;
#undef OSL
    }
}

// ---------------- host ----------------------------------------------------------------------
extern "C" void kernel_launch(void* const* d_in, const int* in_sizes, int n_in,
                              void* d_out, int out_size, void* d_ws, size_t ws_size,
                              hipStream_t stream) {
    const float* img = (const float*)d_in[0];
    float* out = (float*)d_out;
    // single fused kernel: v-blur (from L2-resident img) + h-blur + DoG, one write per output
    hipLaunchKernelGGL(fused_dog_kernel, dim3(6144), dim3(128), 0, stream, img, out);
}

// Round 6
// 330.827 us; speedup vs baseline: 2.1081x; 2.1081x over previous
//
#include <hip/hip_runtime.h>
#include <cmath>
#include <cstddef>

#define BATCH 8
#define CH    3
#define HH    512
#define WW    512
#define NSLOT 7
#define HWX   (HH*WW)
#define RR    8        // rows per block
#define LROW  640      // LDS floats per row slot (max LEN = 636)

__device__ __host__ __forceinline__ int refl(int i, int n) {
    i = i < 0 ? -i : i;
    return i >= n ? 2 * n - 2 - i : i;
}

// ---------------- compile-time Gaussian weights -----------------
constexpr double cexp_(double x) {           // e^x for x in [-13, 0]
    double r = x / 64.0, term = 1.0, s = 1.0;
    for (int i = 1; i < 26; ++i) { term *= r / i; s += term; }
    for (int j = 0; j < 6; ++j) s *= s;      // s = (e^{x/64})^64
    return s;
}

// h-pass weights: effective size KSE = KS + Z (Z zero taps prepended so the
// staged row's left pad is a multiple of 4 floats). Real taps at [8+Z, 8+KSE).
template<int KSE> struct WArr { float w[KSE + 16]; };

template<int KSE, int KS>
constexpr WArr<KSE> make_wz(double sg) {
    WArr<KSE> a{};
    double tmp[KS] = {};
    double sum = 0.0;
    for (int t = 0; t < KS; ++t) {
        const double ax = (double)(t - KS / 2);
        tmp[t] = cexp_(-(ax * ax) / (2.0 * sg * sg));
        sum += tmp[t];
    }
    for (int i = 0; i < KSE + 16; ++i) a.w[i] = 0.0f;
    constexpr int Z = KSE - KS;
    for (int t = 0; t < KS; ++t) a.w[8 + Z + t] = (float)(tmp[t] / sum);
    return a;
}

// per scale: KS {7,9,17,31,59,117}, PD=KS/2 {3,4,8,15,29,58}
// PDA = round-up-4 {4,4,8,16,32,60}; Z = PDA-PD {1,0,0,1,3,2}; KSE = KS+Z
__device__ constexpr WArr<8>   CW0 = make_wz<8,   7>(0.6);
__device__ constexpr WArr<9>   CW1 = make_wz<9,   9>(1.2);
__device__ constexpr WArr<17>  CW2 = make_wz<17, 17>(2.4);
__device__ constexpr WArr<32>  CW3 = make_wz<32, 31>(4.8);
__device__ constexpr WArr<62>  CW4 = make_wz<62, 59>(9.6);
__device__ constexpr WArr<119> CW5 = make_wz<119,117>(19.2);

// v-pass weights: exact taps at [0, KS), compile-time indexed -> literals
template<int KS> struct CVArr { float w[KS]; };

template<int KS>
constexpr CVArr<KS> make_cv(double sg) {
    CVArr<KS> a{};
    double tmp[KS] = {};
    double sum = 0.0;
    for (int t = 0; t < KS; ++t) {
        const double ax = (double)(t - KS / 2);
        tmp[t] = cexp_(-(ax * ax) / (2.0 * sg * sg));
        sum += tmp[t];
    }
    for (int t = 0; t < KS; ++t) a.w[t] = (float)(tmp[t] / sum);
    return a;
}

__device__ constexpr CVArr<7>   CV0 = make_cv<7>(0.6);
__device__ constexpr CVArr<9>   CV1 = make_cv<9>(1.2);
__device__ constexpr CVArr<17>  CV2 = make_cv<17>(2.4);
__device__ constexpr CVArr<31>  CV3 = make_cv<31>(4.8);
__device__ constexpr CVArr<59>  CV4 = make_cv<59>(9.6);
__device__ constexpr CVArr<117> CV5 = make_cv<117>(19.2);

// ---------------- horizontal blur: 4 px/thread, 6-slot rolling window ----------------------
template<int KSE>
__device__ __forceinline__ float4 hblur4(const float* __restrict__ lrow, int xt,
                                         const WArr<KSE>& W)
{
    constexpr int NT = (KSE + 3) & ~3;
    constexpr int G  = NT / 4;           // tap groups
    constexpr int NR = G + 2;            // float4 slots needed: 0..G+1
    const float4* l4 = (const float4*)lrow;
    float cb[24];                        // 6 rolling float4 slots
#pragma unroll
    for (int s = 0; s < (NR < 4 ? NR : 4); ++s) {   // up-front prefetch
        const float4 t = l4[xt + s];
        cb[(s % 6) * 4 + 0] = t.x; cb[(s % 6) * 4 + 1] = t.y;
        cb[(s % 6) * 4 + 2] = t.z; cb[(s % 6) * 4 + 3] = t.w;
    }
    float a[4] = {0.f, 0.f, 0.f, 0.f};
#pragma unroll
    for (int g = 0; g < G; ++g) {
        if (g + 4 < NR) {                // read ahead (folds at unroll)
            const int sl = (g + 4) % 6;
            const float4 t = l4[xt + g + 4];
            cb[sl * 4 + 0] = t.x; cb[sl * 4 + 1] = t.y;
            cb[sl * 4 + 2] = t.z; cb[sl * 4 + 3] = t.w;
        }
#pragma unroll
        for (int tt = 0; tt < 4; ++tt) {
            const float wt = W.w[8 + 4 * g + tt];        // compile-time constant
#pragma unroll
            for (int j = 0; j < 4; ++j) {
                const int q    = tt + j;                 // 0..6
                const int slot = (g + (q >> 2)) % 6;
                a[j] = fmaf(wt, cb[slot * 4 + (q & 3)], a[j]);
            }
        }
    }
    return make_float4(a[0], a[1], a[2], a[3]);
}

// ---------------- vertical sweep: 8 rows x float4, 4-deep prefetch ring --------------------
// g[r] = sum_i W[i] * img[refl(y0+r-PD+i)]; loaded row t covers taps i = t-r.
// Bounded prefetch ring pb[4]: >=4 independent global loads always in flight
// while FMAing the previous batch -> counted-vmcnt pipelining, low VGPR.
template<int KS, int PD, bool CAP>
__device__ __forceinline__ void vsweep(const float* __restrict__ ibase, int xt, int y0,
                                       const CVArr<KS>& W, float4* __restrict__ ac,
                                       float4* __restrict__ gp)
{
    constexpr int T = KS + RR - 1;
#pragma unroll
    for (int r = 0; r < RR; ++r) ac[r] = make_float4(0.f, 0.f, 0.f, 0.f);

    float4 pb[4];
#pragma unroll
    for (int i = 0; i < 4; ++i) {
        const int t0 = i < T ? i : T - 1;
        pb[i] = ((const float4*)(ibase + (size_t)refl(y0 - PD + t0, HH) * WW))[xt];
    }
    constexpr int TB = (T + 3) & ~3;
#pragma unroll
    for (int tb = 0; tb < TB; tb += 4) {
#pragma unroll
        for (int i = 0; i < 4; ++i) {
            const int t = tb + i;                        // compile-time
            if (t < T) {
                const float4 v = pb[i];
                if (t + 4 < T)                           // issue next before FMAs
                    pb[i] = ((const float4*)(ibase +
                              (size_t)refl(y0 - PD + t + 4, HH) * WW))[xt];
                if (CAP && t - PD >= 0 && t - PD < RR) gp[t - PD] = v;  // raw img row
#pragma unroll
                for (int r = 0; r < RR; ++r) {
                    const int ti = t - r;                // tap index, compile-time
                    if (ti >= 0 && ti < KS) {
                        const float wt = W.w[ti];        // literal
                        ac[r].x = fmaf(wt, v.x, ac[r].x);
                        ac[r].y = fmaf(wt, v.y, ac[r].y);
                        ac[r].z = fmaf(wt, v.z, ac[r].z);
                        ac[r].w = fmaf(wt, v.w, ac[r].w);
                    }
                }
            }
        }
    }
}

// ---------------- fully fused kernel, sequential scales --------------------------------------
// Block = 128 threads = 8 rows x full width. Per scale s: v-sweep (global, L2-resident)
// -> LDS (one shared 8-row buffer, reused; halos by LDS reflection) -> h-blur + DoG chain
// in registers -> final store. Grid co-resident: 1536 blocks = 6 blocks/CU (12 waves),
// LDS 20480 B -> 8-block cap. Per-XCD input slice = 3 channel images = 3 MB < 4 MB L2.
__global__ __launch_bounds__(128, 3) void fused_dog2_kernel(const float* __restrict__ img,
                                                            float* __restrict__ out)
{
    __shared__ __align__(16) float L[RR * LROW];
    const int xt  = threadIdx.x;          // 0..127 (float4 col)
    const int n   = blockIdx.x;
    const int xcd = n & 7;
    const int k   = n >> 3;               // 0..191
    const int bcg = k / 64;               // 0..2
    const int yg  = k - bcg * 64;         // 0..63
    const int y0  = yg * RR;
    const int bc  = bcg * 8 + xcd;        // 0..23
    const int b = bc / CH, c = bc - b * CH;
    const float* ibase = img + (size_t)bc * HWX;
    float4* out4 = (float4*)out;

    float4 gp[RR];                        // previous gaussian (DoG chain), starts as raw img
    float4 ac[RR];                        // v-blur accumulators (reused per scale)

#define DOSCALE(S, KS, PD, PDA, LEN, CVW, CWW, CAP)                                 \
    {                                                                               \
        vsweep<KS, PD, CAP>(ibase, xt, y0, CVW, ac, gp);                            \
        __syncthreads();            /* prior scale's H reads of L are done */       \
        _Pragma("unroll")                                                           \
        for (int r = 0; r < RR; ++r)                                                \
            ((float4*)(L + r * LROW + PDA))[xt] = ac[r];                            \
        __syncthreads();            /* interior visible for halo reflection */      \
        {                                                                           \
            constexpr int RH = LEN - PDA - 512;                                     \
            for (int idx = xt; idx < RR * PDA; idx += 128) {                        \
                const int r = idx / PDA, i2 = idx - r * PDA;                        \
                L[r * LROW + i2] = L[r * LROW + 2 * PDA - i2];                      \
            }                                                                       \
            for (int idx = xt; idx < RR * RH; idx += 128) {                         \
                const int r = idx / RH, i2 = idx - r * RH;                          \
                const int d = PDA + 512 + i2;                                       \
                L[r * LROW + d] = L[r * LROW + 2 * PDA + 1022 - d];                 \
            }                                                                       \
        }                                                                           \
        __syncthreads();                                                            \
        _Pragma("unroll")                                                           \
        for (int r = 0; r < RR; ++r) {                                              \
            const float4 g = hblur4<sizeof(CWW.w) / 4 - 16>(L + r * LROW, xt, CWW); \
            float4* o = out4 + ((size_t)((b * NSLOT + S) * CH) + c) * (HWX / 4)     \
                        + (size_t)(y0 + r) * (WW / 4) + xt;                         \
            *o = make_float4(g.x - gp[r].x, g.y - gp[r].y,                          \
                             g.z - gp[r].z, g.w - gp[r].w);                         \
            gp[r] = g;                                                              \
        }                                                                           \
    }

    DOSCALE(0,   7,  3,  4, 524, CV0, CW0, true)
    DOSCALE(1,   9,  4,  4, 528, CV1, CW1, false)
    DOSCALE(2,  17,  8,  8, 536, CV2, CW2, false)
    DOSCALE(3,  31, 15, 16, 548, CV3, CW3, false)
    DOSCALE(4,  59, 29, 32, 580, CV4, CW4, false)
    DOSCALE(5, 117, 58, 60, 636, CV5, CW5, false)
#undef DOSCALE

    // slot 6 = last gaussian itself
#pragma unroll
    for (int r = 0; r < RR; ++r) {
        float4* o = out4 + ((size_t)((b * NSLOT + 6) * CH) + c) * (HWX / 4)
                    + (size_t)(y0 + r) * (WW / 4) + xt;
        *o = gp[r];
    }
}

// ---------------- host ----------------------------------------------------------------------
extern "C" void kernel_launch(void* const* d_in, const int* in_sizes, int n_in,
                              void* d_out, int out_size, void* d_ws, size_t ws_size,
                              hipStream_t stream) {
    const float* img = (const float*)d_in[0];
    float* out = (float*)d_out;
    // single fused kernel: 1536 = 8 xcd * 3 channel-groups * 64 row-groups
    hipLaunchKernelGGL(fused_dog2_kernel, dim3(1536), dim3(128), 0, stream, img, out);
}